// Round 5
// baseline (192.795 us; speedup 1.0000x reference)
//
#include <hip/hip_runtime.h>
#include <math.h>

// JointAttentionMemoryBank via fp16 MFMA.  out = W @ softmax(W^T x / sqrt(D))
//   B=16 N=4096 D=128 M=1536.  fp32 in/out.
// R11: dual-path A-streams + skewed p1 + fast prep.
//  R10 post-mortem: per-CU pipe sums == wall (no overlap). LDS unit is per-CU
//  shared: any A-stream through it costs ~12cyc/b128 regardless of broadcast.
//  Fixes:
//  - WT read from GLOBAL (L1-cached, 64B/cyc path) -> p1 has no LDS dep, so
//    p1-mfma(q+1) hoists into segment q (skew with plain dbuf, 1 barrier/sess).
//  - WD staged to LDS (128B/cyc path) -> two A-streams on two pipes, ~45K cyc
//    each per CU, in parallel with MFMA 49K and VALU/TRANS ~80K.
//  - 4-wave blocks (NT=64), 1024 blocks; target <=170 VGPR -> 3 waves/SIMD,
//    12 waves/CU, blocks at different sessions break lockstep.
//  - Register-P (permlane32_swap relayout, R10-verified), m-partitioned p2,
//    cross-wm c-reduce via staging LDS at end. Conflict-free by construction.
//  - PREP REWRITE: old gather prep ~65us (total-main across R6..R10). Now 48
//    blocks stage 32m x 128d W-tile to LDS via coalesced row reads, emit both
//    fragment arrays from LDS. Fragment layouts unchanged (R10-verified).
// exp2-folded scale in wt. No-max softmax, P unnormalized fp16, fp32 epilogue.

#define Bdim 16
#define Ndim 4096
#define Ddim 128
#define Mdim 1536
#define NT 64               // rows (n) per block
#define NTHREADS 256        // 4 waves: (wm = w>>1) x (u = w&1)
#define NSESS 24            // m-sessions (64 m each)

typedef __attribute__((ext_vector_type(8)))  _Float16 f16x8;   // 4 VGPRs
typedef __attribute__((ext_vector_type(16))) float    f32x16;  // 32x32 MFMA C/D

union H2 { _Float16 h[2]; unsigned u; };
union F8 { unsigned u[4]; f16x8 v; };

// ---- prep: W (D,M) fp32 -> fragment-ordered fp16 arrays (32x32x16 form) ----
// Layouts identical to R10 (harness-verified):
// wt (phase-1 A = W^T, pre-scaled log2e/sqrt(D)):
//   frag f = (mt32*8 + ks)*64 + l ; m = mt32*32 + (l&31), d = ks*16 + (l>>5)*8 + j
// wd (phase-2 A = W), km-major:
//   frag f = (km*4 + dt)*64 + l ; d = dt*32 + (l&31), m = km*16 + (l>>5)*8 + j
// One block per mt32 (48 blocks): coalesced stage of 32m x 128d tile -> LDS,
// then emit 512 wt frags + 512 wd frags (2 each per thread).
__global__ __launch_bounds__(256)
void jamb_prep(const float* __restrict__ w,
               _Float16* __restrict__ wt,
               _Float16* __restrict__ wd) {
    __shared__ float ts[32 * 132];        // [m][d], +4 pad
    const int t  = threadIdx.x;
    const int mt = blockIdx.x;            // 0..47
    #pragma unroll
    for (int i = 0; i < 16; ++i) {        // 4096 floats, 128B-coalesced rows
        const int f = t + i * 256;
        const int d = f >> 5;
        const int m = f & 31;
        ts[m * 132 + d] = w[(size_t)d * Mdim + mt * 32 + m];
    }
    __syncthreads();
    const float SC = 0.12751742957f;      // log2(e)/sqrt(128)
    #pragma unroll
    for (int h = 0; h < 2; ++h) {         // wt: 2 frags/thread
        const int fr = t + h * 256;       // 0..511
        const int l  = fr & 63;
        const int ks = fr >> 6;           // 0..7
        const int m  = l & 31;
        const int d0 = ks * 16 + (l >> 5) * 8;
        f16x8 pk;
        #pragma unroll
        for (int j = 0; j < 8; ++j)
            pk[j] = (_Float16)(ts[m * 132 + d0 + j] * SC);
        *(f16x8*)&wt[(size_t)((mt * 8 + ks) * 64 + l) * 8] = pk;
    }
    #pragma unroll
    for (int h = 0; h < 2; ++h) {         // wd: 2 frags/thread (km_local = h)
        const int l    = t & 63;
        const int dt   = t >> 6;          // 0..3
        const int km   = mt * 2 + h;
        const int d    = dt * 32 + (l & 31);
        const int mloc = h * 16 + (l >> 5) * 8;
        f16x8 pk;
        #pragma unroll
        for (int j = 0; j < 8; ++j)
            pk[j] = (_Float16)ts[(mloc + j) * 132 + d];
        *(f16x8*)&wd[(size_t)((km * 4 + dt) * 64 + l) * 8] = pk;
    }
}

static __device__ __forceinline__ void glds16(const void* g, void* l) {
    __builtin_amdgcn_global_load_lds(
        (const __attribute__((address_space(1))) unsigned*)g,
        (__attribute__((address_space(3))) unsigned*)l, 16, 0, 0);
}

__global__ __launch_bounds__(NTHREADS, 3)
void jamb_mfma_kernel(const float* __restrict__ x,
                      const _Float16* __restrict__ wt,
                      const _Float16* __restrict__ wd,
                      float* __restrict__ out) {
    __shared__ __align__(16) _Float16 wdbuf[2][8192];   // 32 KB dbuf; c-reduce at end
    __shared__ float sred[2][2][32];                    // [wm][u][l31]

    const int t   = threadIdx.x;
    const int w   = t >> 6;         // wave 0..3
    const int l   = t & 63;
    const int l31 = l & 31;
    const int hi  = l >> 5;
    const int wm  = w >> 1;         // m-owner: session m-tile mt32 = 2q+wm
    const int u   = w & 1;          // n-owner: n = nbase + u*32 + l31

    const int blk   = blockIdx.x;
    const int b     = blk >> 6;             // 64 blocks per batch
    const int nbase = (blk & 63) * NT;

    // ---- x B-fragments (32 n x 128 d), 8 frags = 32 VGPR, loaded once ----
    f16x8 bx[8];
    {
        const float* xr = x + (size_t)(b * Ndim + nbase + u * 32 + l31) * Ddim;
        #pragma unroll
        for (int ks = 0; ks < 8; ++ks) {
            const float* s = xr + ks * 16 + hi * 8;
            const float4 v0 = *(const float4*)s;
            const float4 v1 = *(const float4*)(s + 4);
            f16x8 pk;
            pk[0] = (_Float16)v0.x; pk[1] = (_Float16)v0.y;
            pk[2] = (_Float16)v0.z; pk[3] = (_Float16)v0.w;
            pk[4] = (_Float16)v1.x; pk[5] = (_Float16)v1.y;
            pk[6] = (_Float16)v1.z; pk[7] = (_Float16)v1.w;
            bx[ks] = pk;
        }
    }

    const f16x8* WTg = (const f16x8*)wt;    // read via L1 (global path)
    const char*  wdc = (const char*)wd;
    const int lane16 = l * 16;

    // stage session q's WD 16KB slice into wdbuf[q&1]; 4 async 1KB rounds/wave
    auto stage = [&](int q) {
        char* dst = (char*)&wdbuf[q & 1][0] + w * 4096;
        const char* src = wdc + q * 16384 + w * 4096;
        glds16(src + 0    + lane16, dst + 0);
        glds16(src + 1024 + lane16, dst + 1024);
        glds16(src + 2048 + lane16, dst + 2048);
        glds16(src + 3072 + lane16, dst + 3072);
    };

    float ssum = 0.f;               // softmax partial (own m only), n = u*32+l31
    f32x16 c[4];                    // p2 partials: dt 0..3, own m only
    #pragma unroll
    for (int dt = 0; dt < 4; ++dt) c[dt] = (f32x16)(0.f);

    // ---- prologue: stage(0) || p1-mfma(0) (WT from global; no LDS dep) ----
    stage(0);
    f32x16 acc = (f32x16)(0.f);
    {
        #pragma unroll
        for (int ks = 0; ks < 8; ++ks) {
            const f16x8 fh = WTg[(size_t)((0 + wm) * 8 + ks) * 64 + l];
            acc = __builtin_amdgcn_mfma_f32_32x32x16_f16(fh, bx[ks], acc, 0, 0, 0);
        }
    }
    __syncthreads();                // wdbuf[0] ready (vmcnt drained + all waves)

    #pragma unroll 1
    for (int q = 0; q < NSESS; ++q) {
        // issue next session's async stage + WT loads first (latency hiding)
        f16x8 fhn[8];
        if (q + 1 < NSESS) {
            stage(q + 1);           // into wdbuf[(q+1)&1]: last read in seg q-1
            #pragma unroll
            for (int ks = 0; ks < 8; ++ks)
                fhn[ks] = WTg[(size_t)((2 * (q + 1) + wm) * 8 + ks) * 64 + l];
        }

        // ---- exp + pack + permlane relayout of acc(q) -> register B-frags ----
        unsigned Wg[4][2];
        #pragma unroll
        for (int g = 0; g < 4; ++g) {
            const float e0 = exp2f(acc[4 * g + 0]);   // wt pre-scaled by log2e
            const float e1 = exp2f(acc[4 * g + 1]);
            const float e2 = exp2f(acc[4 * g + 2]);
            const float e3 = exp2f(acc[4 * g + 3]);
            ssum += (e0 + e1) + (e2 + e3);
            H2 pa; pa.h[0] = (_Float16)e0; pa.h[1] = (_Float16)e1;
            H2 pb; pb.h[0] = (_Float16)e2; pb.h[1] = (_Float16)e3;
            Wg[g][0] = pa.u; Wg[g][1] = pb.u;
        }
        F8 pf[2];
        #pragma unroll
        for (int k2 = 0; k2 < 2; ++k2) {
            unsigned a0 = Wg[2 * k2][0], b0 = Wg[2 * k2 + 1][0];
            unsigned a1 = Wg[2 * k2][1], b1 = Wg[2 * k2 + 1][1];
            asm volatile("v_permlane32_swap_b32 %0, %1" : "+v"(a0), "+v"(b0));
            asm volatile("v_permlane32_swap_b32 %0, %1" : "+v"(a1), "+v"(b1));
            pf[k2].u[0] = a0; pf[k2].u[1] = a1;
            pf[k2].u[2] = b0; pf[k2].u[3] = b1;
        }

        // ---- p2(q): A = WD from LDS slice, B = pf regs; 4 chains x 2 deep ----
        {
            const _Float16* WDl = &wdbuf[q & 1][0];
            #pragma unroll
            for (int k2 = 0; k2 < 2; ++k2) {
                const int kk = 2 * wm + k2;       // session-local 16-m index
                #pragma unroll
                for (int dt = 0; dt < 4; ++dt) {
                    const f16x8 a = *(const f16x8*)(WDl + ((kk * 4 + dt) * 64 + l) * 8);
                    c[dt] = __builtin_amdgcn_mfma_f32_32x32x16_f16(a, pf[k2].v, c[dt], 0, 0, 0);
                }
            }
        }

        // ---- p1-mfma(q+1): independent of exp/p2 streams above ----
        if (q + 1 < NSESS) {
            f32x16 an = (f32x16)(0.f);
            #pragma unroll
            for (int ks = 0; ks < 8; ++ks)
                an = __builtin_amdgcn_mfma_f32_32x32x16_f16(fhn[ks], bx[ks], an, 0, 0, 0);
            acc = an;
        }
        __syncthreads();    // publish stage(q+1); retire reads of wdbuf[q&1]
    }

    // ---- reductions: fold hi halves; cross-wm via LDS ----
    ssum += __shfl_xor(ssum, 32, 64);
    if (hi == 0) sred[wm][u][l31] = ssum;
    float* cxbase = (float*)&wdbuf[0][0];           // 32 KB, free now
    if (wm == 1) {
        float* cx = cxbase + u * 4096;
        #pragma unroll
        for (int dt = 0; dt < 4; ++dt) {
            #pragma unroll
            for (int g = 0; g < 4; ++g) {
                float4 v;
                v.x = c[dt][4 * g + 0]; v.y = c[dt][4 * g + 1];
                v.z = c[dt][4 * g + 2]; v.w = c[dt][4 * g + 3];
                *(float4*)(cx + ((dt * 4 + g) * 64 + l) * 4) = v;
            }
        }
    }
    __syncthreads();
    if (wm == 0) {
        const float inv = 1.f / (sred[0][u][l31] + sred[1][u][l31]);
        const float* cx = cxbase + u * 4096;
        float* ob = out + (size_t)(b * Ndim + nbase + u * 32 + l31) * Ddim;
        #pragma unroll
        for (int dt = 0; dt < 4; ++dt) {
            #pragma unroll
            for (int g = 0; g < 4; ++g) {
                const float4 pc = *(const float4*)(cx + ((dt * 4 + g) * 64 + l) * 4);
                float4 o;
                o.x = (c[dt][4 * g + 0] + pc.x) * inv;
                o.y = (c[dt][4 * g + 1] + pc.y) * inv;
                o.z = (c[dt][4 * g + 2] + pc.z) * inv;
                o.w = (c[dt][4 * g + 3] + pc.w) * inv;
                *(float4*)(ob + dt * 32 + g * 8 + hi * 4) = o;
            }
        }
    }
}

extern "C" void kernel_launch(void* const* d_in, const int* in_sizes, int n_in,
                              void* d_out, int out_size, void* d_ws, size_t ws_size,
                              hipStream_t stream) {
    const float* x = (const float*)d_in[0];   // (B,N,D)
    const float* w = (const float*)d_in[1];   // (1,D,M)
    float* out = (float*)d_out;
    (void)in_sizes; (void)n_in; (void)out_size; (void)ws_size;

    _Float16* wt = (_Float16*)d_ws;           // 384 KB
    _Float16* wd = wt + Ddim * Mdim;          // 384 KB

    jamb_prep<<<dim3(48), dim3(256), 0, stream>>>(w, wt, wd);
    jamb_mfma_kernel<<<dim3((Bdim * Ndim) / NT), dim3(NTHREADS), 0, stream>>>(x, wt, wd, out);
}

// Round 6
// 151.247 us; speedup vs baseline: 1.2747x; 1.2747x over previous
//
#include <hip/hip_runtime.h>
#include <math.h>

// JointAttentionMemoryBank via fp16 MFMA.  out = W @ softmax(W^T x / sqrt(D))
//   B=16 N=4096 D=128 M=1536.  fp32 in/out.
// R12 = R6 (67.5us champion) + two surgical changes:
//  1. T2 XOR-swizzle on xs/Pbuf (pad dropped, stride 128 f16; 16B slot XOR'd
//     with row&7). R6's 7.86M bank-conflict cycles (~31K cyc/CU, ~19% of wall)
//     come from the 16-row x 4-quad b128 access shape where row never enters
//     the bank index. Swizzle applied consistently to all 4 access sites
//     (reg-staged writes -> both-sides consistency trivial). LDS 35.8->33 KB.
//  2. exp2 fold: wt pre-scaled by log2(e)/sqrt(D); softmax uses exp2f.
// Everything else (sessions, barriers, fragment layouts, epilogue, prep
// structure, launch config) byte-identical to R6.
// Ledger (R7-R11): restructures lose -> pipes sum not overlap; occupancy needs
// VGPR+AGPR <= 128/wave (only this 16x16 layout fits: 60+64); total-main
// ~60us is fixed harness overhead, not prep.

#define Bdim 16
#define Ndim 4096
#define Ddim 128
#define Mdim 1536
#define NT 64               // rows (n) per block
#define NTHREADS 256        // 4 waves
#define NSESS 12            // m-sessions
#define SESS_M 128          // m per session (8 m-tiles; 2 per wave)
#define XPAD 128            // xs row stride f16 (no pad; swizzled)
#define PPAD 128            // Pbuf row stride f16 (no pad; swizzled)
#define NFRAG 24576         // fragments per W array = D*M/8

// T2 swizzle: f16-index domain; XOR 16B-slot bits (3..5) with row&7.
#define SW(row, off) ((off) ^ (((row) & 7) << 3))

typedef __attribute__((ext_vector_type(8))) _Float16 f16x8;  // 4 VGPRs
typedef __attribute__((ext_vector_type(4))) _Float16 f16x4;  // 8 B
typedef __attribute__((ext_vector_type(4))) float    f32x4;  // MFMA C/D

// ---- prep: W (D,M) fp32 -> fragment-ordered fp16 arrays (gather form) ----
// wt (phase-1 A = W^T, pre-scaled log2e/sqrt(D) so exp(S) == exp2(S')):
//   frag f = (mt*4 + ks)*64 + lane ; m = mt*16 + (lane&15), d = ks*32 + (lane>>4)*8 + j
// wd (phase-2 A = W):
//   frag f = (dt*48 + km)*64 + lane ; d = dt*16 + (lane&15), m = km*32 + (lane>>4)*8 + j
__global__ void jamb_prep(const float* __restrict__ w,
                          _Float16* __restrict__ wt,
                          _Float16* __restrict__ wd) {
    const int tid = blockIdx.x * 256 + threadIdx.x;   // [0, 2*NFRAG)
    const float SC = 0.12751742957f;                  // log2(e)/sqrt(128)
    if (tid < NFRAG) {                                // blocks 0..95: wt
        const int f    = tid;
        const int lane = f & 63;
        const int fs   = f >> 6;
        const int ks   = fs & 3;          // 0..3
        const int mt   = fs >> 2;         // 0..95
        const int m    = mt * 16 + (lane & 15);
        const int d0   = ks * 32 + (lane >> 4) * 8;
        f16x8 pk;
        #pragma unroll
        for (int j = 0; j < 8; ++j)
            pk[j] = (_Float16)(w[(size_t)(d0 + j) * Mdim + m] * SC);
        *(f16x8*)&wt[(size_t)f * 8] = pk;
    } else {                                          // blocks 96..191: wd
        const int f    = tid - NFRAG;
        const int lane = f & 63;
        const int fs   = f >> 6;
        const int km   = fs % 48;         // 0..47
        const int dt   = fs / 48;         // 0..7
        const int d    = dt * 16 + (lane & 15);
        const int m0   = km * 32 + (lane >> 4) * 8;
        const float* src = w + (size_t)d * Mdim + m0;
        const float4 v0 = *(const float4*)src;
        const float4 v1 = *(const float4*)(src + 4);
        f16x8 pk;
        pk[0] = (_Float16)v0.x; pk[1] = (_Float16)v0.y;
        pk[2] = (_Float16)v0.z; pk[3] = (_Float16)v0.w;
        pk[4] = (_Float16)v1.x; pk[5] = (_Float16)v1.y;
        pk[6] = (_Float16)v1.z; pk[7] = (_Float16)v1.w;
        *(f16x8*)&wd[(size_t)f * 8] = pk;
    }
}

__global__ __launch_bounds__(NTHREADS, 4)
void jamb_mfma_kernel(const float* __restrict__ x,
                      const _Float16* __restrict__ wt,
                      const _Float16* __restrict__ wd,
                      float* __restrict__ out) {
    __shared__ __align__(16) _Float16 xs[NT * XPAD];    // 16384 B
    __shared__ __align__(16) _Float16 Pbuf[NT * PPAD];  // 16384 B
    __shared__ float redsum[4][4][16];                  // 1024 B   (total 33792 B)

    const int t    = threadIdx.x;
    const int w    = t >> 6;        // wave 0..3
    const int l    = t & 63;
    const int c16  = l & 15;
    const int quad = l >> 4;

    const int blk   = blockIdx.x;
    const int b     = blk >> 6;             // 64 blocks per batch
    const int nbase = (blk & 63) * NT;

    // ---- stage x tile -> LDS fp16 (coalesced float4 reads; swizzled write) ----
    {
        const float* xb = x + (size_t)(b * Ndim + nbase) * Ddim;
        #pragma unroll
        for (int i = 0; i < 8; ++i) {
            const int f   = t + i * 256;        // float4 index, [0,2048)
            const int row = f >> 5;             // 32 float4 per row
            const int c4  = (f & 31) * 4;       // f16 col, multiple of 4
            const float4 v = *(const float4*)(xb + row * Ddim + c4);
            f16x4 pk;
            pk[0] = (_Float16)v.x; pk[1] = (_Float16)v.y;
            pk[2] = (_Float16)v.z; pk[3] = (_Float16)v.w;
            *(f16x4*)&xs[row * XPAD + SW(row, c4)] = pk;
        }
    }
    __syncthreads();

    const f16x8* WT = (const f16x8*)wt;
    const f16x8* WD = (const f16x8*)wd;

    float sums[4] = {0.f, 0.f, 0.f, 0.f};        // per n-tile unnormalized softmax sums
    f32x4 c[2][4];                               // phase-2 acc: 2 d-tiles x 4 n-tiles
    #pragma unroll
    for (int i = 0; i < 2; ++i)
        #pragma unroll
        for (int nt = 0; nt < 4; ++nt) c[i][nt] = (f32x4){0.f, 0.f, 0.f, 0.f};

    #pragma unroll 1
    for (int q = 0; q < NSESS; ++q) {
        const int mtb = q * 8 + w * 2;           // this wave's global m-tile base

        // ---- phase 1: S tiles for 2 m-tiles x 4 n-tiles ----
        f32x4 acc[2][4];
        #pragma unroll
        for (int i = 0; i < 2; ++i)
            #pragma unroll
            for (int nt = 0; nt < 4; ++nt) acc[i][nt] = (f32x4){0.f, 0.f, 0.f, 0.f};

        #pragma unroll
        for (int s = 0; s < 4; ++s) {
            const f16x8 fh0 = WT[((mtb + 0) * 4 + s) * 64 + l];
            const f16x8 fh1 = WT[((mtb + 1) * 4 + s) * 64 + l];
            f16x8 bx[4];
            #pragma unroll
            for (int nt = 0; nt < 4; ++nt) {
                const int row = nt * 16 + c16;
                bx[nt] = *(const f16x8*)&xs[row * XPAD + SW(row, s * 32 + quad * 8)];
            }
            #pragma unroll
            for (int nt = 0; nt < 4; ++nt) {
                acc[0][nt] = __builtin_amdgcn_mfma_f32_16x16x32_f16(fh0, bx[nt], acc[0][nt], 0, 0, 0);
                acc[1][nt] = __builtin_amdgcn_mfma_f32_16x16x32_f16(fh1, bx[nt], acc[1][nt], 0, 0, 0);
            }
        }

        // ---- exp2 + P write (session-local m; no max subtraction) ----
        #pragma unroll
        for (int i = 0; i < 2; ++i) {
            const int mloc = (w * 2 + i) * 16 + quad * 4;   // multiple of 4
            #pragma unroll
            for (int nt = 0; nt < 4; ++nt) {
                const float e0 = exp2f(acc[i][nt][0]);   // wt pre-scaled by log2e
                const float e1 = exp2f(acc[i][nt][1]);
                const float e2 = exp2f(acc[i][nt][2]);
                const float e3 = exp2f(acc[i][nt][3]);
                sums[nt] += (e0 + e1) + (e2 + e3);
                f16x4 pk;
                pk[0] = (_Float16)e0; pk[1] = (_Float16)e1;
                pk[2] = (_Float16)e2; pk[3] = (_Float16)e3;
                const int row = nt * 16 + c16;
                *(f16x4*)&Pbuf[row * PPAD + SW(row, mloc)] = pk;
            }
        }
        __syncthreads();   // P session published

        // ---- phase 2: 4 m-ksteps; wave owns d-tiles 2w, 2w+1 ----
        #pragma unroll
        for (int sk = 0; sk < 4; ++sk) {
            const f16x8 a0 = WD[((2 * w)     * 48 + q * 4 + sk) * 64 + l];
            const f16x8 a1 = WD[((2 * w + 1) * 48 + q * 4 + sk) * 64 + l];
            f16x8 p[4];
            #pragma unroll
            for (int nt = 0; nt < 4; ++nt) {
                const int row = nt * 16 + c16;
                p[nt] = *(const f16x8*)&Pbuf[row * PPAD + SW(row, sk * 32 + quad * 8)];
            }
            #pragma unroll
            for (int nt = 0; nt < 4; ++nt) {
                c[0][nt] = __builtin_amdgcn_mfma_f32_16x16x32_f16(a0, p[nt], c[0][nt], 0, 0, 0);
                c[1][nt] = __builtin_amdgcn_mfma_f32_16x16x32_f16(a1, p[nt], c[1][nt], 0, 0, 0);
            }
        }
        __syncthreads();   // Pbuf free for next session
    }

    // ---- softmax sums: cross-quad butterfly, cross-wave via LDS ----
    #pragma unroll
    for (int nt = 0; nt < 4; ++nt) {
        sums[nt] += __shfl_xor(sums[nt], 16, 64);
        sums[nt] += __shfl_xor(sums[nt], 32, 64);
    }
    if (quad == 0) {
        #pragma unroll
        for (int nt = 0; nt < 4; ++nt) redsum[w][nt][c16] = sums[nt];
    }
    __syncthreads();

    float inv[4];
    #pragma unroll
    for (int nt = 0; nt < 4; ++nt)
        inv[nt] = 1.f / ((redsum[0][nt][c16] + redsum[1][nt][c16]) +
                         (redsum[2][nt][c16] + redsum[3][nt][c16]));

    // ---- epilogue: C row = d-in-tile = quad*4+reg, col n = c16 ----
    #pragma unroll
    for (int dt2 = 0; dt2 < 2; ++dt2) {
        #pragma unroll
        for (int nt = 0; nt < 4; ++nt) {
            float* op = out + (size_t)(b * Ndim + nbase + nt * 16 + c16) * Ddim
                           + (2 * w + dt2) * 16 + quad * 4;
            float4 o;
            o.x = c[dt2][nt][0] * inv[nt];
            o.y = c[dt2][nt][1] * inv[nt];
            o.z = c[dt2][nt][2] * inv[nt];
            o.w = c[dt2][nt][3] * inv[nt];
            *(float4*)op = o;
        }
    }
}

extern "C" void kernel_launch(void* const* d_in, const int* in_sizes, int n_in,
                              void* d_out, int out_size, void* d_ws, size_t ws_size,
                              hipStream_t stream) {
    const float* x = (const float*)d_in[0];   // (B,N,D)
    const float* w = (const float*)d_in[1];   // (1,D,M)
    float* out = (float*)d_out;
    (void)in_sizes; (void)n_in; (void)out_size; (void)ws_size;

    _Float16* wt = (_Float16*)d_ws;           // 384 KB
    _Float16* wd = wt + Ddim * Mdim;          // 384 KB

    jamb_prep<<<dim3((2 * NFRAG) / 256), dim3(256), 0, stream>>>(w, wt, wd);  // 192 blocks
    jamb_mfma_kernel<<<dim3((Bdim * Ndim) / NT), dim3(NTHREADS), 0, stream>>>(x, wt, wd, out);
}

// Round 7
// 138.673 us; speedup vs baseline: 1.3903x; 1.0907x over previous
//
#include <hip/hip_runtime.h>
#include <math.h>

// JointAttentionMemoryBank via fp16 MFMA.  out = W @ softmax(W^T x / sqrt(D))
//   B=16 N=4096 D=128 M=1536.  fp32 in/out.
// R13 = R6 (67.5us champion, verbatim numerics/layout/traffic) + one change:
//   SKEW: phase1-MFMA(q+1) moved into session q's phase-2 segment. Legal
//   because p1-MFMA reads only xs (immutable) + WT (global), never Pbuf.
//   Segments become: [A: p2(q) 32 MFMA + p1mfma(q+1) 32 MFMA, two load
//   streams] | barrierB | [exp+Pwrite(q+1), VALU-only, short] | barrierA.
//   Traffic, LDS size (35.8KB, 4 blk/CU), register peak (acc+c=64 AGPR)
//   all identical to R6. This is R7's skew (ran correct; regressed only
//   from SESS_M=64 traffic) applied at SESS_M=128 = equal traffic.
// Ledger: bank-conflict counter is STRUCTURAL for wave64 b128 shapes
//   (R12: swizzle moved every byte, counter identical 7864320) - not a lever.
//   exp2f (no underscore) is the slow precise path - keep __expf.
//   VGPR+AGPR must stay <=128/wave (4 waves/SIMD).

#define Bdim 16
#define Ndim 4096
#define Ddim 128
#define Mdim 1536
#define NT 64               // rows (n) per block
#define NTHREADS 256        // 4 waves
#define NSESS 12            // m-sessions
#define SESS_M 128          // m per session (8 m-tiles; 2 per wave)
#define XPAD 136            // xs row stride fp16 (128+8)
#define PPAD 136            // Pbuf row stride fp16 (128+8)
#define NFRAG 24576         // fragments per W array = D*M/8

typedef __attribute__((ext_vector_type(8))) _Float16 f16x8;  // 4 VGPRs
typedef __attribute__((ext_vector_type(4))) _Float16 f16x4;  // 8 B
typedef __attribute__((ext_vector_type(4))) float    f32x4;  // MFMA C/D

// ---- prep: W (D,M) fp32 -> fragment-ordered fp16 arrays (gather form) ----
// wt (phase-1 A = W^T, pre-scaled 1/sqrt(D)):
//   frag f = (mt*4 + ks)*64 + lane ; m = mt*16 + (lane&15), d = ks*32 + (lane>>4)*8 + j
// wd (phase-2 A = W):
//   frag f = (dt*48 + km)*64 + lane ; d = dt*16 + (lane&15), m = km*32 + (lane>>4)*8 + j
__global__ void jamb_prep(const float* __restrict__ w,
                          _Float16* __restrict__ wt,
                          _Float16* __restrict__ wd) {
    const int tid = blockIdx.x * 256 + threadIdx.x;   // [0, 2*NFRAG)
    const float SC = 0.08838834764831843f;            // 1/sqrt(128)
    if (tid < NFRAG) {                                // blocks 0..95: wt
        const int f    = tid;
        const int lane = f & 63;
        const int fs   = f >> 6;
        const int ks   = fs & 3;          // 0..3
        const int mt   = fs >> 2;         // 0..95
        const int m    = mt * 16 + (lane & 15);
        const int d0   = ks * 32 + (lane >> 4) * 8;
        f16x8 pk;
        #pragma unroll
        for (int j = 0; j < 8; ++j)
            pk[j] = (_Float16)(w[(size_t)(d0 + j) * Mdim + m] * SC);
        *(f16x8*)&wt[(size_t)f * 8] = pk;
    } else {                                          // blocks 96..191: wd
        const int f    = tid - NFRAG;
        const int lane = f & 63;
        const int fs   = f >> 6;
        const int km   = fs % 48;         // 0..47
        const int dt   = fs / 48;         // 0..7
        const int d    = dt * 16 + (lane & 15);
        const int m0   = km * 32 + (lane >> 4) * 8;
        const float* src = w + (size_t)d * Mdim + m0;
        const float4 v0 = *(const float4*)src;
        const float4 v1 = *(const float4*)(src + 4);
        f16x8 pk;
        pk[0] = (_Float16)v0.x; pk[1] = (_Float16)v0.y;
        pk[2] = (_Float16)v0.z; pk[3] = (_Float16)v0.w;
        pk[4] = (_Float16)v1.x; pk[5] = (_Float16)v1.y;
        pk[6] = (_Float16)v1.z; pk[7] = (_Float16)v1.w;
        *(f16x8*)&wd[(size_t)f * 8] = pk;
    }
}

__global__ __launch_bounds__(NTHREADS, 4)
void jamb_mfma_kernel(const float* __restrict__ x,
                      const _Float16* __restrict__ wt,
                      const _Float16* __restrict__ wd,
                      float* __restrict__ out) {
    __shared__ __align__(16) _Float16 xs[NT * XPAD];    // 17408 B
    __shared__ __align__(16) _Float16 Pbuf[NT * PPAD];  // 17408 B
    __shared__ float redsum[4][4][16];                  // 1024 B   (total 35840 B)

    const int t    = threadIdx.x;
    const int w    = t >> 6;        // wave 0..3
    const int l    = t & 63;
    const int c16  = l & 15;
    const int quad = l >> 4;

    const int blk   = blockIdx.x;
    const int b     = blk >> 6;             // 64 blocks per batch
    const int nbase = (blk & 63) * NT;

    // ---- stage x tile -> LDS fp16 (coalesced float4 reads) ----
    {
        const float* xb = x + (size_t)(b * Ndim + nbase) * Ddim;
        #pragma unroll
        for (int i = 0; i < 8; ++i) {
            const int f   = t + i * 256;        // float4 index, [0,2048)
            const int row = f >> 5;             // 32 float4 per row
            const int c4  = (f & 31) * 4;
            const float4 v = *(const float4*)(xb + row * Ddim + c4);
            f16x4 pk;
            pk[0] = (_Float16)v.x; pk[1] = (_Float16)v.y;
            pk[2] = (_Float16)v.z; pk[3] = (_Float16)v.w;
            *(f16x4*)&xs[row * XPAD + c4] = pk;
        }
    }
    __syncthreads();

    const f16x8* WT = (const f16x8*)wt;
    const f16x8* WD = (const f16x8*)wd;

    float sums[4] = {0.f, 0.f, 0.f, 0.f};        // per n-tile unnormalized softmax sums
    f32x4 c[2][4];                               // phase-2 acc: 2 d-tiles x 4 n-tiles
    #pragma unroll
    for (int i = 0; i < 2; ++i)
        #pragma unroll
        for (int nt = 0; nt < 4; ++nt) c[i][nt] = (f32x4){0.f, 0.f, 0.f, 0.f};

    f32x4 acc[2][4];                             // phase-1 S acc (skewed: holds q+1)

    // ---- phase-1 MFMA for session q: acc = W^T x for 2 m-tiles x 4 n-tiles ----
    auto p1mfma = [&](int q) {
        const int mtb = q * 8 + w * 2;           // this wave's global m-tile base
        #pragma unroll
        for (int i = 0; i < 2; ++i)
            #pragma unroll
            for (int nt = 0; nt < 4; ++nt) acc[i][nt] = (f32x4){0.f, 0.f, 0.f, 0.f};
        #pragma unroll
        for (int s = 0; s < 4; ++s) {
            const f16x8 fh0 = WT[((mtb + 0) * 4 + s) * 64 + l];
            const f16x8 fh1 = WT[((mtb + 1) * 4 + s) * 64 + l];
            f16x8 bx[4];
            #pragma unroll
            for (int nt = 0; nt < 4; ++nt)
                bx[nt] = *(const f16x8*)&xs[(nt * 16 + c16) * XPAD + s * 32 + quad * 8];
            #pragma unroll
            for (int nt = 0; nt < 4; ++nt) {
                acc[0][nt] = __builtin_amdgcn_mfma_f32_16x16x32_f16(fh0, bx[nt], acc[0][nt], 0, 0, 0);
                acc[1][nt] = __builtin_amdgcn_mfma_f32_16x16x32_f16(fh1, bx[nt], acc[1][nt], 0, 0, 0);
            }
        }
    };

    // ---- exp + P write (session-local m; no max subtraction) ----
    auto expwrite = [&]() {
        #pragma unroll
        for (int i = 0; i < 2; ++i) {
            const int mloc = (w * 2 + i) * 16 + quad * 4;
            #pragma unroll
            for (int nt = 0; nt < 4; ++nt) {
                const float e0 = __expf(acc[i][nt][0]);
                const float e1 = __expf(acc[i][nt][1]);
                const float e2 = __expf(acc[i][nt][2]);
                const float e3 = __expf(acc[i][nt][3]);
                sums[nt] += (e0 + e1) + (e2 + e3);
                f16x4 pk;
                pk[0] = (_Float16)e0; pk[1] = (_Float16)e1;
                pk[2] = (_Float16)e2; pk[3] = (_Float16)e3;
                *(f16x4*)&Pbuf[(nt * 16 + c16) * PPAD + mloc] = pk;
            }
        }
    };

    // ---- phase 2 for session q: 4 m-ksteps; wave owns d-tiles 2w, 2w+1 ----
    auto p2 = [&](int q) {
        #pragma unroll
        for (int sk = 0; sk < 4; ++sk) {
            const f16x8 a0 = WD[((2 * w)     * 48 + q * 4 + sk) * 64 + l];
            const f16x8 a1 = WD[((2 * w + 1) * 48 + q * 4 + sk) * 64 + l];
            f16x8 p[4];
            #pragma unroll
            for (int nt = 0; nt < 4; ++nt)
                p[nt] = *(const f16x8*)&Pbuf[(nt * 16 + c16) * PPAD + sk * 32 + quad * 8];
            #pragma unroll
            for (int nt = 0; nt < 4; ++nt) {
                c[0][nt] = __builtin_amdgcn_mfma_f32_16x16x32_f16(a0, p[nt], c[0][nt], 0, 0, 0);
                c[1][nt] = __builtin_amdgcn_mfma_f32_16x16x32_f16(a1, p[nt], c[1][nt], 0, 0, 0);
            }
        }
    };

    // ---- skewed pipeline: p2(q) || p1mfma(q+1) share a segment ----
    // Hazards: Pwrite(q+1) occurs after barrierB (p2(q) reads retired);
    // p2(q+1) reads after barrierA which follows Pwrite(q+1). p1mfma
    // touches only xs (immutable) + WT (global) -> legal inside p2's segment.
    p1mfma(0);
    expwrite();
    #pragma unroll 1
    for (int q = 0; q < NSESS; ++q) {
        __syncthreads();               // A: P(q) published
        p2(q);
        if (q + 1 < NSESS) p1mfma(q + 1);
        __syncthreads();               // B: Pbuf reads retired
        if (q + 1 < NSESS) expwrite();
    }

    // ---- softmax sums: cross-quad butterfly, cross-wave via LDS ----
    #pragma unroll
    for (int nt = 0; nt < 4; ++nt) {
        sums[nt] += __shfl_xor(sums[nt], 16, 64);
        sums[nt] += __shfl_xor(sums[nt], 32, 64);
    }
    if (quad == 0) {
        #pragma unroll
        for (int nt = 0; nt < 4; ++nt) redsum[w][nt][c16] = sums[nt];
    }
    __syncthreads();

    float inv[4];
    #pragma unroll
    for (int nt = 0; nt < 4; ++nt)
        inv[nt] = 1.f / ((redsum[0][nt][c16] + redsum[1][nt][c16]) +
                         (redsum[2][nt][c16] + redsum[3][nt][c16]));

    // ---- epilogue: C row = d-in-tile = quad*4+reg, col n = c16 ----
    #pragma unroll
    for (int dt2 = 0; dt2 < 2; ++dt2) {
        #pragma unroll
        for (int nt = 0; nt < 4; ++nt) {
            float* op = out + (size_t)(b * Ndim + nbase + nt * 16 + c16) * Ddim
                           + (2 * w + dt2) * 16 + quad * 4;
            float4 o;
            o.x = c[dt2][nt][0] * inv[nt];
            o.y = c[dt2][nt][1] * inv[nt];
            o.z = c[dt2][nt][2] * inv[nt];
            o.w = c[dt2][nt][3] * inv[nt];
            *(float4*)op = o;
        }
    }
}

extern "C" void kernel_launch(void* const* d_in, const int* in_sizes, int n_in,
                              void* d_out, int out_size, void* d_ws, size_t ws_size,
                              hipStream_t stream) {
    const float* x = (const float*)d_in[0];   // (B,N,D)
    const float* w = (const float*)d_in[1];   // (1,D,M)
    float* out = (float*)d_out;
    (void)in_sizes; (void)n_in; (void)out_size; (void)ws_size;

    _Float16* wt = (_Float16*)d_ws;           // 384 KB
    _Float16* wd = wt + Ddim * Mdim;          // 384 KB

    jamb_prep<<<dim3((2 * NFRAG) / 256), dim3(256), 0, stream>>>(w, wt, wd);  // 192 blocks
    jamb_mfma_kernel<<<dim3((Bdim * Ndim) / NT), dim3(NTHREADS), 0, stream>>>(x, wt, wd, out);
}